// Round 1
// baseline (539.400 us; speedup 1.0000x reference)
//
#include <hip/hip_runtime.h>

#define N_NODES 10000
#define N_EDGES 160000

typedef __attribute__((ext_vector_type(8))) __bf16 bf16x8;
typedef __attribute__((ext_vector_type(4))) float f32x4;

static __device__ __forceinline__ unsigned short f2bf(float x) {
    union { float f; unsigned u; } un;
    un.f = x;
    unsigned r = un.u + 0x7fffu + ((un.u >> 16) & 1u);  // RNE
    return (unsigned short)(r >> 16);
}

static __device__ __forceinline__ float bf2f(unsigned short h) {
    union { unsigned u; float f; } un;
    un.u = ((unsigned)h) << 16;
    return un.f;
}

// ---------------------------------------------------------------------------
// Prep: transpose weights to [n][k] bf16 so MFMA B-fragments are contiguous 16B
// ---------------------------------------------------------------------------
__global__ __launch_bounds__(256) void prep_kernel(
    const float* __restrict__ W1, const float* __restrict__ W2,
    const float* __restrict__ Wr,
    unsigned short* __restrict__ W1T, unsigned short* __restrict__ W2T,
    unsigned short* __restrict__ WrT)
{
    int tid = blockIdx.x * 256 + threadIdx.x;   // grid covers 131072
    if (tid < 131072) {                          // W2T [1024][128]
        int n = tid >> 7, k = tid & 127;
        W2T[tid] = f2bf(W2[k * 1024 + n]);
    }
    if (tid < 16384) {                           // W1T [128][128]
        int n = tid >> 7, k = tid & 127;
        W1T[tid] = f2bf(W1[k * 128 + n]);
    }
    if (tid < 32768) {                           // WrT [1024][32]
        int n = tid >> 5, k = tid & 31;
        WrT[tid] = f2bf(Wr[k * 1024 + n]);
    }
}

// ---------------------------------------------------------------------------
// Rc = R1*f1 + R2*f2 + R3*f3 (bf16), fsum = f1+f2+f3, degree histogram
// ---------------------------------------------------------------------------
__global__ __launch_bounds__(256) void rc_kernel(
    const float* __restrict__ R1, const float* __restrict__ R2,
    const float* __restrict__ R3,
    const float* __restrict__ f1, const float* __restrict__ f2,
    const float* __restrict__ f3,
    const int* __restrict__ eidx,           // idx_i = eidx[0..E)
    unsigned short* __restrict__ Rc, float* __restrict__ fsum,
    int* __restrict__ cnt)
{
    int tid = blockIdx.x * 256 + threadIdx.x;   // E*32 threads
    int e = tid >> 5, k = tid & 31;
    if (e >= N_EDGES) return;
    float a = f1[e], b = f2[e], c = f3[e];
    float rc = R1[tid] * a + R2[tid] * b + R3[tid] * c;
    Rc[tid] = f2bf(rc);
    if (k == 0) {
        fsum[e] = a + b + c;
        atomicAdd(&cnt[eidx[e]], 1);
    }
}

// ---------------------------------------------------------------------------
// Exclusive scan of degree counts -> offs[0..N], cursor copy for the fill
// ---------------------------------------------------------------------------
__global__ __launch_bounds__(1024) void scan_kernel(
    const int* __restrict__ cnt, int* __restrict__ offs,
    int* __restrict__ cursor, int n)
{
    __shared__ int wsum[16];
    __shared__ int s_running;
    int t = threadIdx.x, lane = t & 63, wid = t >> 6;
    if (t == 0) s_running = 0;
    __syncthreads();
    for (int base = 0; base < n; base += 1024) {
        int idx = base + t;
        int vv = (idx < n) ? cnt[idx] : 0;
        // inclusive wave scan
        int x = vv;
        #pragma unroll
        for (int o = 1; o < 64; o <<= 1) {
            int y = __shfl_up(x, o);
            if (lane >= o) x += y;
        }
        if (lane == 63) wsum[wid] = x;
        __syncthreads();
        if (wid == 0) {
            int wv = (lane < 16) ? wsum[lane] : 0;
            #pragma unroll
            for (int o = 1; o < 16; o <<= 1) {
                int y = __shfl_up(wv, o);
                if (lane >= o) wv += y;
            }
            if (lane < 16) wsum[lane] = wv;   // inclusive over waves
        }
        __syncthreads();
        int wbase = (wid > 0) ? wsum[wid - 1] : 0;
        int incl = x + wbase;
        int run = s_running;
        if (idx < n) {
            int ex = run + incl - vv;
            offs[idx] = ex;
            cursor[idx] = ex;
        }
        __syncthreads();
        if (t == 0) s_running = run + wsum[15];
        __syncthreads();
    }
    if (t == 0) offs[n] = s_running;
}

// ---------------------------------------------------------------------------
// CSR fill: bucket edge ids by destination node
// ---------------------------------------------------------------------------
__global__ __launch_bounds__(256) void fill_kernel(
    const int* __restrict__ eidx, int* __restrict__ cursor,
    int* __restrict__ elist)
{
    int e = blockIdx.x * 256 + threadIdx.x;
    if (e >= N_EDGES) return;
    int i = eidx[e];
    int slot = atomicAdd(&cursor[i], 1);
    elist[slot] = e;
}

// ---------------------------------------------------------------------------
// phi = silu(s@W1 + b1) @ W2 + b2   -> bf16 [N, 1024]
// block = 16-node tile, 4 waves; stage-1 h kept in LDS
// ---------------------------------------------------------------------------
__global__ __launch_bounds__(256) void phi_kernel(
    const float* __restrict__ s, const unsigned short* __restrict__ W1T,
    const float* __restrict__ b1, const unsigned short* __restrict__ W2T,
    const float* __restrict__ b2, unsigned short* __restrict__ phi)
{
    __shared__ float h_lds[16][132];   // pad 132: 2-way banks (free), 16B-aligned rows
    int t = threadIdx.x, lane = t & 63, w = t >> 6;
    int quad = lane >> 4, l16 = lane & 15;
    int m0 = blockIdx.x * 16;

    // ---- stage 1: h = silu(s@W1 + b1), N=128 (wave covers 32 cols) ----
    f32x4 acc[2] = {{0.f, 0.f, 0.f, 0.f}, {0.f, 0.f, 0.f, 0.f}};
    #pragma unroll
    for (int ks = 0; ks < 4; ++ks) {
        int k0 = ks * 32 + quad * 8;
        const float* sp = s + (size_t)(m0 + l16) * 128 + k0;
        bf16x8 af;
        #pragma unroll
        for (int j = 0; j < 8; ++j) af[j] = (__bf16)sp[j];
        #pragma unroll
        for (int b = 0; b < 2; ++b) {
            int col = w * 32 + b * 16 + l16;
            bf16x8 bf = *reinterpret_cast<const bf16x8*>(W1T + col * 128 + k0);
            acc[b] = __builtin_amdgcn_mfma_f32_16x16x32_bf16(af, bf, acc[b], 0, 0, 0);
        }
    }
    #pragma unroll
    for (int b = 0; b < 2; ++b) {
        int col = w * 32 + b * 16 + l16;
        float bb = b1[col];
        #pragma unroll
        for (int r = 0; r < 4; ++r) {
            int row = quad * 4 + r;
            float val = acc[b][r] + bb;
            h_lds[row][col] = val / (1.0f + __expf(-val));   // silu
        }
    }
    __syncthreads();

    // ---- stage 2: phi = h@W2 + b2, N=1024 (wave covers 256 cols) ----
    bf16x8 afr[4];
    #pragma unroll
    for (int ks = 0; ks < 4; ++ks) {
        int k0 = ks * 32 + quad * 8;
        const float* hp = &h_lds[l16][k0];
        #pragma unroll
        for (int j = 0; j < 8; ++j) afr[ks][j] = (__bf16)hp[j];
    }
    #pragma unroll
    for (int t16 = 0; t16 < 16; ++t16) {
        int col = w * 256 + t16 * 16 + l16;
        f32x4 a2 = {0.f, 0.f, 0.f, 0.f};
        #pragma unroll
        for (int ks = 0; ks < 4; ++ks) {
            bf16x8 bf = *reinterpret_cast<const bf16x8*>(W2T + col * 128 + ks * 32 + quad * 8);
            a2 = __builtin_amdgcn_mfma_f32_16x16x32_bf16(afr[ks], bf, a2, 0, 0, 0);
        }
        float bb = b2[col];
        #pragma unroll
        for (int r = 0; r < 4; ++r) {
            int row = quad * 4 + r;
            phi[(size_t)(m0 + row) * 1024 + col] = f2bf(a2[r] + bb);
        }
    }
}

// ---------------------------------------------------------------------------
// Main fused kernel: one block per destination node.
// 8 waves; wave w owns feature cols f = w*16 + (lane&15) across all 8 chunks.
// Per 16-edge tile: one MFMA (K=32) per chunk computes W-part, epilogue does
// phi[j]*W, geometry (unit vecs + cross products), register accumulation.
// No atomics anywhere.
// ---------------------------------------------------------------------------
__global__ __launch_bounds__(512) void msg_kernel(
    const float* __restrict__ s, const float* __restrict__ v,
    const int* __restrict__ eidx,                 // idx_j = eidx + E
    const unsigned short* __restrict__ Rc, const float* __restrict__ fsum,
    const unsigned short* __restrict__ phi, const unsigned short* __restrict__ WrT,
    const float* __restrict__ br,
    const int* __restrict__ offs, const int* __restrict__ elist,
    const float* __restrict__ u1, const float* __restrict__ u2,
    const float* __restrict__ u3,
    float* __restrict__ out0, float* __restrict__ out1)
{
    int node = blockIdx.x;
    int t = threadIdx.x, lane = t & 63, w = t >> 6;   // 8 waves
    int quad = lane >> 4, l16 = lane & 15;
    int fcol = w * 16 + l16;                          // this lane's feature col
    const int* idx_j = eidx + N_EDGES;

    // B-fragments (WrT) + bias, constant across tiles: chunk c -> col c*128+fcol
    bf16x8 bfrag[8];
    float brv[8];
    #pragma unroll
    for (int c = 0; c < 8; ++c) {
        int col = c * 128 + fcol;
        bfrag[c] = *reinterpret_cast<const bf16x8*>(WrT + col * 32 + quad * 8);
        brv[c] = br[col];
    }

    int e0 = offs[node], e1 = offs[node + 1];

    __shared__ int   sj[16];
    __shared__ float sfs[16];
    __shared__ float su[16][9];

    float ds_acc = 0.f;
    float dv0 = 0.f, dv1 = 0.f, dv2 = 0.f;

    for (int eb = e0; eb < e1; eb += 16) {
        __syncthreads();
        if (t < 16) {
            int e = eb + t;
            if (e < e1) {
                int eid = elist[e];
                sj[t] = idx_j[eid];
                sfs[t] = fsum[eid];
                su[t][0] = u1[eid * 3 + 0]; su[t][1] = u1[eid * 3 + 1]; su[t][2] = u1[eid * 3 + 2];
                su[t][3] = u2[eid * 3 + 0]; su[t][4] = u2[eid * 3 + 1]; su[t][5] = u2[eid * 3 + 2];
                su[t][6] = u3[eid * 3 + 0]; su[t][7] = u3[eid * 3 + 1]; su[t][8] = u3[eid * 3 + 2];
            } else {
                sj[t] = 0; sfs[t] = 0.f;
                #pragma unroll
                for (int d = 0; d < 9; ++d) su[t][d] = 0.f;
            }
        }
        __syncthreads();

        // A-fragment: 16 edges x K=32 of Rc (zero for padded rows)
        bf16x8 af;
        int er = eb + l16;
        if (er < e1) {
            int eid = elist[er];
            af = *reinterpret_cast<const bf16x8*>(Rc + (size_t)eid * 32 + quad * 8);
        } else {
            #pragma unroll
            for (int j = 0; j < 8; ++j) af[j] = (__bf16)0.f;
        }

        f32x4 acc[8];
        #pragma unroll
        for (int c = 0; c < 8; ++c) {
            f32x4 z = {0.f, 0.f, 0.f, 0.f};
            acc[c] = __builtin_amdgcn_mfma_f32_16x16x32_bf16(af, bfrag[c], z, 0, 0, 0);
        }

        // epilogue: lane owns rows quad*4 .. quad*4+3 at col fcol
        #pragma unroll
        for (int r = 0; r < 4; ++r) {
            int row = quad * 4 + r;
            if (eb + row >= e1) continue;       // padded row
            int j = sj[row];
            float fs = sfs[row];
            const unsigned short* pj = phi + (size_t)j * 1024 + fcol;
            float x[8];
            #pragma unroll
            for (int c = 0; c < 8; ++c) {
                float Wv = acc[c][r] + brv[c] * fs;
                x[c] = bf2f(pj[c * 128]) * Wv;
            }
            const float* vp = v + (size_t)j * 384 + fcol;
            float vjx = vp[0], vjy = vp[128], vjz = vp[256];
            float u1x = su[row][0], u1y = su[row][1], u1z = su[row][2];
            float u2x = su[row][3], u2y = su[row][4], u2z = su[row][5];
            float u3x = su[row][6], u3y = su[row][7], u3z = su[row][8];

            ds_acc += x[0];
            // dv[d] += vj[d]*x_vv + sum_k u_k[d]*x_vsk + sum_k (vj x u_k)[d]*x_vck
            dv0 += vjx * x[1] + u1x * x[2] + u2x * x[3] + u3x * x[4]
                 + x[5] * (vjy * u1z - vjz * u1y)
                 + x[6] * (vjy * u2z - vjz * u2y)
                 + x[7] * (vjy * u3z - vjz * u3y);
            dv1 += vjy * x[1] + u1y * x[2] + u2y * x[3] + u3y * x[4]
                 + x[5] * (vjz * u1x - vjx * u1z)
                 + x[6] * (vjz * u2x - vjx * u2z)
                 + x[7] * (vjz * u3x - vjx * u3z);
            dv2 += vjz * x[1] + u1z * x[2] + u2z * x[3] + u3z * x[4]
                 + x[5] * (vjx * u1y - vjy * u1x)
                 + x[6] * (vjx * u2y - vjy * u2x)
                 + x[7] * (vjx * u3y - vjy * u3x);
        }
    }

    // reduce the 4 row-groups (lanes f, f+16, f+32, f+48 share the same fcol)
    ds_acc += __shfl_xor(ds_acc, 16); ds_acc += __shfl_xor(ds_acc, 32);
    dv0 += __shfl_xor(dv0, 16); dv0 += __shfl_xor(dv0, 32);
    dv1 += __shfl_xor(dv1, 16); dv1 += __shfl_xor(dv1, 32);
    dv2 += __shfl_xor(dv2, 16); dv2 += __shfl_xor(dv2, 32);

    if (quad == 0) {
        size_t so = (size_t)node * 128 + fcol;
        out0[so] = s[so] + ds_acc;
        size_t vo = (size_t)node * 384 + fcol;
        out1[vo]       = v[vo]       + dv0;
        out1[vo + 128] = v[vo + 128] + dv1;
        out1[vo + 256] = v[vo + 256] + dv2;
    }
}

// ---------------------------------------------------------------------------
extern "C" void kernel_launch(void* const* d_in, const int* in_sizes, int n_in,
                              void* d_out, int out_size, void* d_ws, size_t ws_size,
                              hipStream_t stream) {
    const float* s  = (const float*)d_in[0];
    const float* v  = (const float*)d_in[1];
    const float* R1 = (const float*)d_in[2];
    const float* R2 = (const float*)d_in[3];
    const float* R3 = (const float*)d_in[4];
    const float* f1 = (const float*)d_in[5];
    const float* f2 = (const float*)d_in[6];
    const float* f3 = (const float*)d_in[7];
    const float* u1 = (const float*)d_in[8];
    const float* u2 = (const float*)d_in[9];
    const float* u3 = (const float*)d_in[10];
    const int*  eix = (const int*)d_in[11];
    const float* W1 = (const float*)d_in[12];
    const float* b1 = (const float*)d_in[13];
    const float* W2 = (const float*)d_in[14];
    const float* b2 = (const float*)d_in[15];
    const float* Wr = (const float*)d_in[16];
    const float* br = (const float*)d_in[17];

    char* ws = (char*)d_ws;
    size_t off = 0;
    auto alloc = [&](size_t bytes) -> void* {
        void* p = ws + off;
        off = (off + bytes + 255) & ~(size_t)255;
        return p;
    };
    int* cnt    = (int*)alloc((size_t)N_NODES * 4);
    int* offs   = (int*)alloc((size_t)(N_NODES + 1) * 4);
    int* cursor = (int*)alloc((size_t)N_NODES * 4);
    int* elist  = (int*)alloc((size_t)N_EDGES * 4);
    unsigned short* Rc  = (unsigned short*)alloc((size_t)N_EDGES * 32 * 2);
    float* fsum = (float*)alloc((size_t)N_EDGES * 4);
    unsigned short* phi = (unsigned short*)alloc((size_t)N_NODES * 1024 * 2);
    unsigned short* W1T = (unsigned short*)alloc(128 * 128 * 2);
    unsigned short* W2T = (unsigned short*)alloc(1024 * 128 * 2);
    unsigned short* WrT = (unsigned short*)alloc(1024 * 32 * 2);
    (void)ws_size; (void)in_sizes; (void)n_in; (void)out_size;

    float* out0 = (float*)d_out;
    float* out1 = out0 + (size_t)N_NODES * 128;

    hipMemsetAsync(cnt, 0, (size_t)N_NODES * 4, stream);
    prep_kernel<<<512, 256, 0, stream>>>(W1, W2, Wr, W1T, W2T, WrT);
    rc_kernel<<<20000, 256, 0, stream>>>(R1, R2, R3, f1, f2, f3, eix, Rc, fsum, cnt);
    scan_kernel<<<1, 1024, 0, stream>>>(cnt, offs, cursor, N_NODES);
    fill_kernel<<<625, 256, 0, stream>>>(eix, cursor, elist);
    phi_kernel<<<625, 256, 0, stream>>>(s, W1T, b1, W2T, b2, phi);
    msg_kernel<<<10000, 512, 0, stream>>>(s, v, eix, Rc, fsum, phi, WrT, br,
                                          offs, elist, u1, u2, u3, out0, out1);
}

// Round 2
// 416.746 us; speedup vs baseline: 1.2943x; 1.2943x over previous
//
#include <hip/hip_runtime.h>

#define N_NODES 10000
#define N_EDGES 160000
#define MAXT    20000   // >= sum(ceil(deg/16)) <= (E + 15*N)/16 = 19375
#define MSG_GRID 2500   // x8 strided tiles = 20000 slots

typedef __attribute__((ext_vector_type(8))) __bf16 bf16x8;
typedef __attribute__((ext_vector_type(8))) unsigned short u16x8;
typedef __attribute__((ext_vector_type(4))) float f32x4;

static __device__ __forceinline__ unsigned short f2bf(float x) {
    union { float f; unsigned u; } un;
    un.f = x;
    unsigned r = un.u + 0x7fffu + ((un.u >> 16) & 1u);  // RNE
    return (unsigned short)(r >> 16);
}

static __device__ __forceinline__ float bf2f(unsigned short h) {
    union { unsigned u; float f; } un;
    un.u = ((unsigned)h) << 16;
    return un.f;
}

// ---------------------------------------------------------------------------
// Weights -> bf16 transposed [n][k] (contiguous 16B MFMA B-fragments)
// ---------------------------------------------------------------------------
__global__ __launch_bounds__(256) void prep_kernel(
    const float* __restrict__ W1, const float* __restrict__ W2,
    const float* __restrict__ Wr,
    unsigned short* __restrict__ W1T, unsigned short* __restrict__ W2T,
    unsigned short* __restrict__ WrT)
{
    int tid = blockIdx.x * 256 + threadIdx.x;   // 131072 threads
    if (tid < 131072) {                          // W2T [1024][128]
        int n = tid >> 7, k = tid & 127;
        W2T[tid] = f2bf(W2[k * 1024 + n]);
    }
    if (tid < 16384) {                           // W1T [128][128]
        int n = tid >> 7, k = tid & 127;
        W1T[tid] = f2bf(W1[k * 128 + n]);
    }
    if (tid < 32768) {                           // WrT [1024][32]
        int n = tid >> 5, k = tid & 31;
        WrT[tid] = f2bf(Wr[k * 1024 + n]);
    }
}

// ---------------------------------------------------------------------------
// out0 = s, out1 = v (msg atomically adds later), vbf2 [N][128][4] bf16
// (x,y,z,pad), and the degree histogram.
// ---------------------------------------------------------------------------
__global__ __launch_bounds__(256) void init_kernel(
    const float* __restrict__ s, const float* __restrict__ v,
    const int* __restrict__ eix,
    float* __restrict__ out0, float* __restrict__ out1,
    unsigned short* __restrict__ vbf2, int* __restrict__ cnt)
{
    int tid = blockIdx.x * 256 + threadIdx.x;   // grid covers N*384
    if (tid < N_NODES * 384) out1[tid] = v[tid];
    if (tid < N_NODES * 128) {
        out0[tid] = s[tid];
        int n = tid >> 7, f = tid & 127;
        ushort4 q;
        q.x = f2bf(v[(size_t)n * 384 + f]);
        q.y = f2bf(v[(size_t)n * 384 + 128 + f]);
        q.z = f2bf(v[(size_t)n * 384 + 256 + f]);
        q.w = 0;
        *reinterpret_cast<ushort4*>(vbf2 + (size_t)tid * 4) = q;
    }
    if (tid < N_EDGES) atomicAdd(&cnt[eix[tid]], 1);
}

// ---------------------------------------------------------------------------
// Dual exclusive scan (degrees + tile counts) + tile worklist emission.
// Single block, 1024 threads, 10 iterations over N.
// ---------------------------------------------------------------------------
__global__ __launch_bounds__(1024) void scan_kernel(
    const int* __restrict__ cnt, int* __restrict__ cursor,
    int* __restrict__ tile_node, int* __restrict__ tile_e0,
    int* __restrict__ tile_cnt, int* __restrict__ ntiles)
{
    __shared__ int ws0[16], ws1[16];
    __shared__ int run0_s, run1_s;
    int t = threadIdx.x, lane = t & 63, wid = t >> 6;
    if (t == 0) { run0_s = 0; run1_s = 0; }
    __syncthreads();
    for (int base = 0; base < N_NODES; base += 1024) {
        int idx = base + t;
        int deg = (idx < N_NODES) ? cnt[idx] : 0;
        int tc = (deg + 15) >> 4;
        int x0 = deg, x1 = tc;
        #pragma unroll
        for (int o = 1; o < 64; o <<= 1) {
            int y0 = __shfl_up(x0, o), y1 = __shfl_up(x1, o);
            if (lane >= o) { x0 += y0; x1 += y1; }
        }
        if (lane == 63) { ws0[wid] = x0; ws1[wid] = x1; }
        __syncthreads();
        if (wid == 0) {
            int w0 = (lane < 16) ? ws0[lane] : 0;
            int w1 = (lane < 16) ? ws1[lane] : 0;
            #pragma unroll
            for (int o = 1; o < 16; o <<= 1) {
                int y0 = __shfl_up(w0, o), y1 = __shfl_up(w1, o);
                if (lane >= o) { w0 += y0; w1 += y1; }
            }
            if (lane < 16) { ws0[lane] = w0; ws1[lane] = w1; }
        }
        __syncthreads();
        int wb0 = wid ? ws0[wid - 1] : 0;
        int wb1 = wid ? ws1[wid - 1] : 0;
        int ex0 = run0_s + wb0 + x0 - deg;
        int ex1 = run1_s + wb1 + x1 - tc;
        if (idx < N_NODES) {
            cursor[idx] = ex0;
            for (int k = 0; k < tc; ++k) {
                tile_node[ex1 + k] = idx;
                tile_e0[ex1 + k]   = ex0 + k * 16;
                int rem = deg - k * 16;
                tile_cnt[ex1 + k]  = rem < 16 ? rem : 16;
            }
        }
        __syncthreads();
        if (t == 0) { run0_s += ws0[15]; run1_s += ws1[15]; }
        __syncthreads();
    }
    if (t == 0) *ntiles = run1_s;
}

// ---------------------------------------------------------------------------
// Scatter pass: 8 threads/edge. Coalesced reads of R/f/u/edge_index; writes
// RcS[slot][32] bf16 and rowdat[slot][12] = {j, fsum, u1xyz, u2xyz, u3xyz, 0}
// at the CSR slot (atomic cursor).
// ---------------------------------------------------------------------------
__global__ __launch_bounds__(256) void scatter_kernel(
    const float* __restrict__ R1, const float* __restrict__ R2,
    const float* __restrict__ R3,
    const float* __restrict__ f1, const float* __restrict__ f2,
    const float* __restrict__ f3,
    const float* __restrict__ u1, const float* __restrict__ u2,
    const float* __restrict__ u3,
    const int* __restrict__ eix, int* __restrict__ cursor,
    unsigned short* __restrict__ RcS, float* __restrict__ rowdat)
{
    int tid = blockIdx.x * 256 + threadIdx.x;   // E*8 threads
    int e = tid >> 3, sub = tid & 7;
    if (e >= N_EDGES) return;
    int lane = threadIdx.x & 63, base = lane & 56;
    float a = f1[e], b = f2[e], c = f3[e];
    int slot = 0;
    if (sub == 0) slot = atomicAdd(&cursor[eix[e]], 1);
    slot = __shfl(slot, base);
    int k0 = sub * 4;
    float4 r1 = *reinterpret_cast<const float4*>(R1 + (size_t)e * 32 + k0);
    float4 r2 = *reinterpret_cast<const float4*>(R2 + (size_t)e * 32 + k0);
    float4 r3 = *reinterpret_cast<const float4*>(R3 + (size_t)e * 32 + k0);
    ushort4 o;
    o.x = f2bf(r1.x * a + r2.x * b + r3.x * c);
    o.y = f2bf(r1.y * a + r2.y * b + r3.y * c);
    o.z = f2bf(r1.z * a + r2.z * b + r3.z * c);
    o.w = f2bf(r1.w * a + r2.w * b + r3.w * c);
    *reinterpret_cast<ushort4*>(RcS + (size_t)slot * 32 + k0) = o;
    if (sub == 0) {
        float2 h;
        h.x = __int_as_float(eix[N_EDGES + e]);   // idx_j
        h.y = a + b + c;                          // fsum
        *reinterpret_cast<float2*>(rowdat + (size_t)slot * 12) = h;
    } else if (sub <= 5) {
        int m = 2 * (sub - 1);
        auto uc = [&](int q) {
            return q < 3 ? u1[(size_t)e * 3 + q]
                 : (q < 6 ? u2[(size_t)e * 3 + q - 3] : u3[(size_t)e * 3 + q - 6]);
        };
        float2 h;
        h.x = uc(m);
        h.y = (m + 1 < 9) ? uc(m + 1) : 0.f;
        *reinterpret_cast<float2*>(rowdat + (size_t)slot * 12 + 2 + m) = h;
    }
}

// ---------------------------------------------------------------------------
// phi = silu(s@W1 + b1) @ W2 + b2, stored CHUNK-MINOR: phi2[n][f][c] bf16
// (c = 0..7 chunk index) so msg reads one 16B vector per (edge,feature).
// M-tile = 64 rows, 4 waves; W2T read once per block (157 blocks -> 40 MB L2).
// ---------------------------------------------------------------------------
__global__ __launch_bounds__(256) void phi_kernel(
    const float* __restrict__ s, const unsigned short* __restrict__ W1T,
    const float* __restrict__ b1, const unsigned short* __restrict__ W2T,
    const float* __restrict__ b2, unsigned short* __restrict__ phi2)
{
    __shared__ unsigned short h_lds[64][136];
    int t = threadIdx.x, lane = t & 63, w = t >> 6;
    int quad = lane >> 4, l16 = lane & 15;
    int m0 = blockIdx.x * 64;

    // ---- stage 1: h = silu(s@W1 + b1) -> LDS (bf16) ----
    int arow = m0 + w * 16 + l16;
    if (arow > N_NODES - 1) arow = N_NODES - 1;
    bf16x8 afr[4];
    #pragma unroll
    for (int ks = 0; ks < 4; ++ks) {
        const float* sp = s + (size_t)arow * 128 + ks * 32 + quad * 8;
        #pragma unroll
        for (int jj = 0; jj < 8; ++jj) afr[ks][jj] = (__bf16)sp[jj];
    }
    #pragma unroll
    for (int cg = 0; cg < 8; ++cg) {
        int col = cg * 16 + l16;
        f32x4 acc = {0.f, 0.f, 0.f, 0.f};
        #pragma unroll
        for (int ks = 0; ks < 4; ++ks) {
            bf16x8 bf = *reinterpret_cast<const bf16x8*>(W1T + (size_t)col * 128 + ks * 32 + quad * 8);
            acc = __builtin_amdgcn_mfma_f32_16x16x32_bf16(afr[ks], bf, acc, 0, 0, 0);
        }
        float bb = b1[col];
        #pragma unroll
        for (int r = 0; r < 4; ++r) {
            int row = w * 16 + quad * 4 + r;
            float val = acc[r] + bb;
            h_lds[row][col] = f2bf(val / (1.f + __expf(-val)));
        }
    }
    __syncthreads();

    // ---- stage 2: phi = h@W2 + b2 ----
    bf16x8 a2[4][4];
    #pragma unroll
    for (int rg = 0; rg < 4; ++rg)
        #pragma unroll
        for (int ks = 0; ks < 4; ++ks)
            a2[rg][ks] = *reinterpret_cast<const bf16x8*>(&h_lds[rg * 16 + l16][ks * 32 + quad * 8]);
    #pragma unroll
    for (int i = 0; i < 16; ++i) {
        int col = (w * 16 + i) * 16 + l16;       // waves cover disjoint 256-col spans
        f32x4 acc2[4] = {{0,0,0,0},{0,0,0,0},{0,0,0,0},{0,0,0,0}};
        #pragma unroll
        for (int ks = 0; ks < 4; ++ks) {
            bf16x8 bf = *reinterpret_cast<const bf16x8*>(W2T + (size_t)col * 128 + ks * 32 + quad * 8);
            #pragma unroll
            for (int rg = 0; rg < 4; ++rg)
                acc2[rg] = __builtin_amdgcn_mfma_f32_16x16x32_bf16(a2[rg][ks], bf, acc2[rg], 0, 0, 0);
        }
        float bb = b2[col];
        int f = col & 127, cc = col >> 7;
        #pragma unroll
        for (int rg = 0; rg < 4; ++rg)
            #pragma unroll
            for (int r = 0; r < 4; ++r) {
                int row = m0 + rg * 16 + quad * 4 + r;
                if (row < N_NODES)
                    phi2[(size_t)row * 1024 + f * 8 + cc] = f2bf(acc2[rg][r] + bb);
            }
    }
}

// ---------------------------------------------------------------------------
// Main msg kernel: flat over 16-edge tiles (balanced). 8 waves; wave w owns
// feature col fcol = w*16+l16 across all 8 chunks. Per tile: 8 MFMAs compute
// the radial filter, epilogue does phi*W + geometry, quad-reduce, atomicAdd
// into out (pre-initialized to s,v). Each block walks 8 strided tiles so the
// WrT fragment registers amortize.
// ---------------------------------------------------------------------------
__global__ __launch_bounds__(512) void msg_kernel(
    const unsigned short* __restrict__ RcS, const float* __restrict__ rowdat,
    const unsigned short* __restrict__ phi2, const unsigned short* __restrict__ vbf2,
    const unsigned short* __restrict__ WrT, const float* __restrict__ br,
    const int* __restrict__ tile_node, const int* __restrict__ tile_e0,
    const int* __restrict__ tile_cnt, const int* __restrict__ ntiles,
    float* __restrict__ out0, float* __restrict__ out1)
{
    int t = threadIdx.x, lane = t & 63, w = t >> 6;
    int quad = lane >> 4, l16 = lane & 15;
    int fcol = w * 16 + l16;
    const int nt = *ntiles;

    bf16x8 bfrag[8];
    float brv[8];
    #pragma unroll
    for (int c = 0; c < 8; ++c) {
        int col = c * 128 + fcol;
        bfrag[c] = *reinterpret_cast<const bf16x8*>(WrT + (size_t)col * 32 + quad * 8);
        brv[c] = br[col];
    }

    __shared__ float srow[16][12];

    #pragma unroll 1
    for (int t8 = 0; t8 < 8; ++t8) {
        int tile = blockIdx.x + t8 * MSG_GRID;
        if (tile >= nt) break;                       // uniform across block
        int node = tile_node[tile], e0 = tile_e0[tile], tcnt = tile_cnt[tile];
        __syncthreads();                             // srow consumed
        if (t < tcnt * 12) ((float*)srow)[t] = rowdat[(size_t)e0 * 12 + t];
        bf16x8 af;
        #pragma unroll
        for (int q = 0; q < 8; ++q) af[q] = (__bf16)0.f;
        if (l16 < tcnt)
            af = *reinterpret_cast<const bf16x8*>(RcS + (size_t)(e0 + l16) * 32 + quad * 8);
        __syncthreads();

        f32x4 acc[8];
        #pragma unroll
        for (int c = 0; c < 8; ++c) {
            f32x4 z = {0.f, 0.f, 0.f, 0.f};
            acc[c] = __builtin_amdgcn_mfma_f32_16x16x32_bf16(af, bfrag[c], z, 0, 0, 0);
        }

        float ds = 0.f, d0 = 0.f, d1 = 0.f, d2 = 0.f;
        #pragma unroll
        for (int r = 0; r < 4; ++r) {
            int row = quad * 4 + r;
            if (row >= tcnt) continue;
            int j = __float_as_int(srow[row][0]);
            float fs = srow[row][1];
            u16x8 ph = *reinterpret_cast<const u16x8*>(phi2 + ((size_t)j * 128 + fcol) * 8);
            ushort4 vb = *reinterpret_cast<const ushort4*>(vbf2 + ((size_t)j * 128 + fcol) * 4);
            float x[8];
            #pragma unroll
            for (int c = 0; c < 8; ++c)
                x[c] = bf2f(ph[c]) * (acc[c][r] + brv[c] * fs);
            float vjx = bf2f(vb.x), vjy = bf2f(vb.y), vjz = bf2f(vb.z);
            float u1x = srow[row][2], u1y = srow[row][3], u1z = srow[row][4];
            float u2x = srow[row][5], u2y = srow[row][6], u2z = srow[row][7];
            float u3x = srow[row][8], u3y = srow[row][9], u3z = srow[row][10];

            ds += x[0];
            d0 += vjx * x[1] + u1x * x[2] + u2x * x[3] + u3x * x[4]
                + x[5] * (vjy * u1z - vjz * u1y)
                + x[6] * (vjy * u2z - vjz * u2y)
                + x[7] * (vjy * u3z - vjz * u3y);
            d1 += vjy * x[1] + u1y * x[2] + u2y * x[3] + u3y * x[4]
                + x[5] * (vjz * u1x - vjx * u1z)
                + x[6] * (vjz * u2x - vjx * u2z)
                + x[7] * (vjz * u3x - vjx * u3z);
            d2 += vjz * x[1] + u1z * x[2] + u2z * x[3] + u3z * x[4]
                + x[5] * (vjx * u1y - vjy * u1x)
                + x[6] * (vjx * u2y - vjy * u2x)
                + x[7] * (vjx * u3y - vjy * u3x);
        }

        ds += __shfl_xor(ds, 16); ds += __shfl_xor(ds, 32);
        d0 += __shfl_xor(d0, 16); d0 += __shfl_xor(d0, 32);
        d1 += __shfl_xor(d1, 16); d1 += __shfl_xor(d1, 32);
        d2 += __shfl_xor(d2, 16); d2 += __shfl_xor(d2, 32);

        if (quad == 0) {
            atomicAdd(&out0[(size_t)node * 128 + fcol], ds);
            size_t vo = (size_t)node * 384 + fcol;
            atomicAdd(&out1[vo], d0);
            atomicAdd(&out1[vo + 128], d1);
            atomicAdd(&out1[vo + 256], d2);
        }
    }
}

// ---------------------------------------------------------------------------
extern "C" void kernel_launch(void* const* d_in, const int* in_sizes, int n_in,
                              void* d_out, int out_size, void* d_ws, size_t ws_size,
                              hipStream_t stream) {
    const float* s  = (const float*)d_in[0];
    const float* v  = (const float*)d_in[1];
    const float* R1 = (const float*)d_in[2];
    const float* R2 = (const float*)d_in[3];
    const float* R3 = (const float*)d_in[4];
    const float* f1 = (const float*)d_in[5];
    const float* f2 = (const float*)d_in[6];
    const float* f3 = (const float*)d_in[7];
    const float* u1 = (const float*)d_in[8];
    const float* u2 = (const float*)d_in[9];
    const float* u3 = (const float*)d_in[10];
    const int*  eix = (const int*)d_in[11];
    const float* W1 = (const float*)d_in[12];
    const float* b1 = (const float*)d_in[13];
    const float* W2 = (const float*)d_in[14];
    const float* b2 = (const float*)d_in[15];
    const float* Wr = (const float*)d_in[16];
    const float* br = (const float*)d_in[17];

    char* ws = (char*)d_ws;
    size_t off = 0;
    auto alloc = [&](size_t bytes) -> void* {
        void* p = ws + off;
        off = (off + bytes + 255) & ~(size_t)255;
        return p;
    };
    int* cnt       = (int*)alloc((size_t)N_NODES * 4);
    int* cursor    = (int*)alloc((size_t)N_NODES * 4);
    int* tile_node = (int*)alloc((size_t)MAXT * 4);
    int* tile_e0   = (int*)alloc((size_t)MAXT * 4);
    int* tile_cnt  = (int*)alloc((size_t)MAXT * 4);
    int* ntiles    = (int*)alloc(4);
    unsigned short* RcS  = (unsigned short*)alloc((size_t)N_EDGES * 32 * 2);
    float* rowdat        = (float*)alloc((size_t)N_EDGES * 12 * 4);
    unsigned short* vbf2 = (unsigned short*)alloc((size_t)N_NODES * 128 * 4 * 2);
    unsigned short* phi2 = (unsigned short*)alloc((size_t)N_NODES * 1024 * 2);
    unsigned short* W1T  = (unsigned short*)alloc(128 * 128 * 2);
    unsigned short* W2T  = (unsigned short*)alloc(1024 * 128 * 2);
    unsigned short* WrT  = (unsigned short*)alloc(1024 * 32 * 2);
    (void)ws_size; (void)in_sizes; (void)n_in; (void)out_size;

    float* out0 = (float*)d_out;
    float* out1 = out0 + (size_t)N_NODES * 128;

    hipMemsetAsync(cnt, 0, (size_t)N_NODES * 4, stream);
    prep_kernel<<<512, 256, 0, stream>>>(W1, W2, Wr, W1T, W2T, WrT);
    init_kernel<<<15000, 256, 0, stream>>>(s, v, eix, out0, out1, vbf2, cnt);
    scan_kernel<<<1, 1024, 0, stream>>>(cnt, cursor, tile_node, tile_e0, tile_cnt, ntiles);
    scatter_kernel<<<5000, 256, 0, stream>>>(R1, R2, R3, f1, f2, f3, u1, u2, u3,
                                             eix, cursor, RcS, rowdat);
    phi_kernel<<<157, 256, 0, stream>>>(s, W1T, b1, W2T, b2, phi2);
    msg_kernel<<<MSG_GRID, 512, 0, stream>>>(RcS, rowdat, phi2, vbf2, WrT, br,
                                             tile_node, tile_e0, tile_cnt, ntiles,
                                             out0, out1);
}

// Round 3
// 366.768 us; speedup vs baseline: 1.4707x; 1.1363x over previous
//
#include <hip/hip_runtime.h>

#define N_NODES 10000
#define N_EDGES 160000
#define MAXT     20000   // >= sum(ceil(deg/16)) <= (E + 15*N)/16 = 19375
#define MSG_GRID 5000    // x4 strided tiles = 20000 slots

typedef __attribute__((ext_vector_type(8))) __bf16 bf16x8;
typedef __attribute__((ext_vector_type(8))) unsigned short u16x8;
typedef __attribute__((ext_vector_type(4))) float f32x4;

static __device__ __forceinline__ unsigned short f2bf(float x) {
    union { float f; unsigned u; } un;
    un.f = x;
    unsigned r = un.u + 0x7fffu + ((un.u >> 16) & 1u);  // RNE
    return (unsigned short)(r >> 16);
}

static __device__ __forceinline__ float bf2f(unsigned short h) {
    union { unsigned u; float f; } un;
    un.u = ((unsigned)h) << 16;
    return un.f;
}

// ---------------------------------------------------------------------------
// Fused init: weight transpose->bf16, out0=s / out1=v, vbf2 packing,
// degree histogram. Grid covers N*384 = 3.84M threads.
// ---------------------------------------------------------------------------
__global__ __launch_bounds__(256) void init_kernel(
    const float* __restrict__ s, const float* __restrict__ v,
    const int* __restrict__ eix,
    const float* __restrict__ W1, const float* __restrict__ W2,
    const float* __restrict__ Wr,
    float* __restrict__ out0, float* __restrict__ out1,
    unsigned short* __restrict__ vbf2, int* __restrict__ cnt,
    unsigned short* __restrict__ W1T, unsigned short* __restrict__ W2T,
    unsigned short* __restrict__ WrT)
{
    int tid = blockIdx.x * 256 + threadIdx.x;
    if (tid < N_NODES * 384) out1[tid] = v[tid];
    if (tid < N_NODES * 128) {
        out0[tid] = s[tid];
        int n = tid >> 7, f = tid & 127;
        ushort4 q;
        q.x = f2bf(v[(size_t)n * 384 + f]);
        q.y = f2bf(v[(size_t)n * 384 + 128 + f]);
        q.z = f2bf(v[(size_t)n * 384 + 256 + f]);
        q.w = 0;
        *reinterpret_cast<ushort4*>(vbf2 + (size_t)tid * 4) = q;
    }
    if (tid < 131072) {                          // W2T [1024][128]
        int n = tid >> 7, k = tid & 127;
        W2T[tid] = f2bf(W2[k * 1024 + n]);
    }
    if (tid < 16384) {                           // W1T [128][128]
        int n = tid >> 7, k = tid & 127;
        W1T[tid] = f2bf(W1[k * 128 + n]);
    }
    if (tid < 32768) {                           // WrT [1024][32]
        int n = tid >> 5, k = tid & 31;
        WrT[tid] = f2bf(Wr[k * 1024 + n]);
    }
    if (tid < N_EDGES) atomicAdd(&cnt[eix[tid]], 1);
}

// ---------------------------------------------------------------------------
// Dual exclusive scan (degrees + tile counts) + tile worklist emission.
// ---------------------------------------------------------------------------
__global__ __launch_bounds__(1024) void scan_kernel(
    const int* __restrict__ cnt, int* __restrict__ cursor,
    int* __restrict__ tile_node, int* __restrict__ tile_e0,
    int* __restrict__ tile_cnt, int* __restrict__ ntiles)
{
    __shared__ int ws0[16], ws1[16];
    __shared__ int run0_s, run1_s;
    int t = threadIdx.x, lane = t & 63, wid = t >> 6;
    if (t == 0) { run0_s = 0; run1_s = 0; }
    __syncthreads();
    for (int base = 0; base < N_NODES; base += 1024) {
        int idx = base + t;
        int deg = (idx < N_NODES) ? cnt[idx] : 0;
        int tc = (deg + 15) >> 4;
        int x0 = deg, x1 = tc;
        #pragma unroll
        for (int o = 1; o < 64; o <<= 1) {
            int y0 = __shfl_up(x0, o), y1 = __shfl_up(x1, o);
            if (lane >= o) { x0 += y0; x1 += y1; }
        }
        if (lane == 63) { ws0[wid] = x0; ws1[wid] = x1; }
        __syncthreads();
        if (wid == 0) {
            int w0 = (lane < 16) ? ws0[lane] : 0;
            int w1 = (lane < 16) ? ws1[lane] : 0;
            #pragma unroll
            for (int o = 1; o < 16; o <<= 1) {
                int y0 = __shfl_up(w0, o), y1 = __shfl_up(w1, o);
                if (lane >= o) { w0 += y0; w1 += y1; }
            }
            if (lane < 16) { ws0[lane] = w0; ws1[lane] = w1; }
        }
        __syncthreads();
        int wb0 = wid ? ws0[wid - 1] : 0;
        int wb1 = wid ? ws1[wid - 1] : 0;
        int ex0 = run0_s + wb0 + x0 - deg;
        int ex1 = run1_s + wb1 + x1 - tc;
        if (idx < N_NODES) {
            cursor[idx] = ex0;
            for (int k = 0; k < tc; ++k) {
                tile_node[ex1 + k] = idx;
                tile_e0[ex1 + k]   = ex0 + k * 16;
                int rem = deg - k * 16;
                tile_cnt[ex1 + k]  = rem < 16 ? rem : 16;
            }
        }
        __syncthreads();
        if (t == 0) { run0_s += ws0[15]; run1_s += ws1[15]; }
        __syncthreads();
    }
    if (t == 0) *ntiles = run1_s;
}

// ---------------------------------------------------------------------------
// rc: Rc = R1*f1 + R2*f2 + R3*f3 (bf16, EDGE order, coalesced), fsum,
// and the CSR fill (elist) via cursor atomics. 8 threads/edge.
// ---------------------------------------------------------------------------
__global__ __launch_bounds__(256) void rc_kernel(
    const float* __restrict__ R1, const float* __restrict__ R2,
    const float* __restrict__ R3,
    const float* __restrict__ f1, const float* __restrict__ f2,
    const float* __restrict__ f3,
    const int* __restrict__ eix, int* __restrict__ cursor,
    unsigned short* __restrict__ Rc, float* __restrict__ fsum,
    int* __restrict__ elist)
{
    int tid = blockIdx.x * 256 + threadIdx.x;   // E*8 threads
    int e = tid >> 3, sub = tid & 7;
    if (e >= N_EDGES) return;
    float a = f1[e], b = f2[e], c = f3[e];
    int k0 = sub * 4;
    float4 r1 = *reinterpret_cast<const float4*>(R1 + (size_t)e * 32 + k0);
    float4 r2 = *reinterpret_cast<const float4*>(R2 + (size_t)e * 32 + k0);
    float4 r3 = *reinterpret_cast<const float4*>(R3 + (size_t)e * 32 + k0);
    ushort4 o;
    o.x = f2bf(r1.x * a + r2.x * b + r3.x * c);
    o.y = f2bf(r1.y * a + r2.y * b + r3.y * c);
    o.z = f2bf(r1.z * a + r2.z * b + r3.z * c);
    o.w = f2bf(r1.w * a + r2.w * b + r3.w * c);
    *reinterpret_cast<ushort4*>(Rc + (size_t)e * 32 + k0) = o;
    if (sub == 0) {
        fsum[e] = a + b + c;
        int slot = atomicAdd(&cursor[eix[e]], 1);
        elist[slot] = e;
    }
}

// ---------------------------------------------------------------------------
// phi = silu(s@W1 + b1) @ W2 + b2, stored CHUNK-MINOR: phi2[n][f][c] bf16.
// Block = 64 rows x 256 cols (grid 157x4) for 4x the round-2 parallelism.
// ---------------------------------------------------------------------------
__global__ __launch_bounds__(256) void phi_kernel(
    const float* __restrict__ s, const unsigned short* __restrict__ W1T,
    const float* __restrict__ b1, const unsigned short* __restrict__ W2T,
    const float* __restrict__ b2, unsigned short* __restrict__ phi2)
{
    __shared__ unsigned short h_lds[64][136];
    int t = threadIdx.x, lane = t & 63, w = t >> 6;
    int quad = lane >> 4, l16 = lane & 15;
    int m0 = (blockIdx.x >> 2) * 64;
    int colg = blockIdx.x & 3;

    // ---- stage 1: h = silu(s@W1 + b1) -> LDS (bf16), full 128 cols ----
    int arow = m0 + w * 16 + l16;
    if (arow > N_NODES - 1) arow = N_NODES - 1;
    bf16x8 afr[4];
    #pragma unroll
    for (int ks = 0; ks < 4; ++ks) {
        const float* sp = s + (size_t)arow * 128 + ks * 32 + quad * 8;
        #pragma unroll
        for (int jj = 0; jj < 8; ++jj) afr[ks][jj] = (__bf16)sp[jj];
    }
    #pragma unroll
    for (int cg = 0; cg < 8; ++cg) {
        int col = cg * 16 + l16;
        f32x4 acc = {0.f, 0.f, 0.f, 0.f};
        #pragma unroll
        for (int ks = 0; ks < 4; ++ks) {
            bf16x8 bf = *reinterpret_cast<const bf16x8*>(W1T + (size_t)col * 128 + ks * 32 + quad * 8);
            acc = __builtin_amdgcn_mfma_f32_16x16x32_bf16(afr[ks], bf, acc, 0, 0, 0);
        }
        float bb = b1[col];
        #pragma unroll
        for (int r = 0; r < 4; ++r) {
            int row = w * 16 + quad * 4 + r;
            float val = acc[r] + bb;
            h_lds[row][col] = f2bf(val / (1.f + __expf(-val)));
        }
    }
    __syncthreads();

    // ---- stage 2: phi = h@W2 + b2 over this block's 256 cols ----
    bf16x8 a2[4][4];
    #pragma unroll
    for (int rg = 0; rg < 4; ++rg)
        #pragma unroll
        for (int ks = 0; ks < 4; ++ks)
            a2[rg][ks] = *reinterpret_cast<const bf16x8*>(&h_lds[rg * 16 + l16][ks * 32 + quad * 8]);
    #pragma unroll
    for (int i = 0; i < 4; ++i) {
        int col = colg * 256 + w * 64 + i * 16 + l16;
        f32x4 acc2[4] = {{0,0,0,0},{0,0,0,0},{0,0,0,0},{0,0,0,0}};
        #pragma unroll
        for (int ks = 0; ks < 4; ++ks) {
            bf16x8 bf = *reinterpret_cast<const bf16x8*>(W2T + (size_t)col * 128 + ks * 32 + quad * 8);
            #pragma unroll
            for (int rg = 0; rg < 4; ++rg)
                acc2[rg] = __builtin_amdgcn_mfma_f32_16x16x32_bf16(a2[rg][ks], bf, acc2[rg], 0, 0, 0);
        }
        float bb = b2[col];
        int f = col & 127, cc = col >> 7;
        #pragma unroll
        for (int rg = 0; rg < 4; ++rg)
            #pragma unroll
            for (int r = 0; r < 4; ++r) {
                int row = m0 + rg * 16 + quad * 4 + r;
                if (row < N_NODES)
                    phi2[(size_t)row * 1024 + f * 8 + cc] = f2bf(acc2[rg][r] + bb);
            }
    }
}

// ---------------------------------------------------------------------------
// Main msg kernel: flat over 16-edge tiles. 8 waves; wave w owns fcol =
// w*16+l16. Branchless epilogue (padded rows have fs=0/j=0/u=0 and zero
// A-rows), double-buffered header -> ONE barrier per tile.
// ---------------------------------------------------------------------------
__global__ __launch_bounds__(512) void msg_kernel(
    const unsigned short* __restrict__ Rc, const float* __restrict__ fsum,
    const int* __restrict__ eix,
    const unsigned short* __restrict__ phi2, const unsigned short* __restrict__ vbf2,
    const unsigned short* __restrict__ WrT, const float* __restrict__ br,
    const int* __restrict__ elist,
    const int* __restrict__ tile_node, const int* __restrict__ tile_e0,
    const int* __restrict__ tile_cnt, const int* __restrict__ ntiles,
    const float* __restrict__ u1, const float* __restrict__ u2,
    const float* __restrict__ u3,
    float* __restrict__ out0, float* __restrict__ out1)
{
    int t = threadIdx.x, lane = t & 63, w = t >> 6;
    int quad = lane >> 4, l16 = lane & 15;
    int fcol = w * 16 + l16;
    const int nt = *ntiles;
    const int* idx_j = eix + N_EDGES;

    bf16x8 bfrag[8];
    float brv[8];
    #pragma unroll
    for (int c = 0; c < 8; ++c) {
        int col = c * 128 + fcol;
        bfrag[c] = *reinterpret_cast<const bf16x8*>(WrT + (size_t)col * 32 + quad * 8);
        brv[c] = br[col];
    }

    __shared__ float srow[2][16][12];  // [j, fsum, u1xyz, u2xyz, u3xyz, pad]

    for (int t4 = 0; t4 < 4; ++t4) {
        int tile = blockIdx.x + t4 * MSG_GRID;
        if (tile >= nt) break;                      // uniform across block
        int node = tile_node[tile], e0 = tile_e0[tile], tcnt = tile_cnt[tile];
        int p = t4 & 1;

        // header: 192 threads, one scattered load each (rows >= tcnt -> 0)
        if (t < 192) {
            int row = t / 12, c = t - row * 12;
            float val = 0.f;
            if (row < tcnt) {
                int eid = elist[e0 + row];
                if (c == 0)      val = __int_as_float(idx_j[eid]);
                else if (c == 1) val = fsum[eid];
                else if (c < 5)  val = u1[(size_t)eid * 3 + c - 2];
                else if (c < 8)  val = u2[(size_t)eid * 3 + c - 5];
                else if (c < 11) val = u3[(size_t)eid * 3 + c - 8];
            }
            srow[p][row][c] = val;
        }

        // A-fragment via elist indirection (zero for padded rows)
        int er = e0 + (l16 < tcnt ? l16 : 0);
        int eid_a = elist[er];
        bf16x8 af;
        if (l16 < tcnt)
            af = *reinterpret_cast<const bf16x8*>(Rc + (size_t)eid_a * 32 + quad * 8);
        else {
            #pragma unroll
            for (int q = 0; q < 8; ++q) af[q] = (__bf16)0.f;
        }

        f32x4 acc[8];
        #pragma unroll
        for (int c = 0; c < 8; ++c) {
            f32x4 z = {0.f, 0.f, 0.f, 0.f};
            acc[c] = __builtin_amdgcn_mfma_f32_16x16x32_bf16(af, bfrag[c], z, 0, 0, 0);
        }

        __syncthreads();   // header visible; epilogue below reads srow[p]

        float ds = 0.f, d0 = 0.f, d1 = 0.f, d2 = 0.f;
        #pragma unroll
        for (int r = 0; r < 4; ++r) {
            int row = quad * 4 + r;
            int j = __float_as_int(srow[p][row][0]);
            float fs = srow[p][row][1];
            u16x8 ph = *reinterpret_cast<const u16x8*>(phi2 + ((size_t)j * 128 + fcol) * 8);
            ushort4 vb = *reinterpret_cast<const ushort4*>(vbf2 + ((size_t)j * 128 + fcol) * 4);
            float x[8];
            #pragma unroll
            for (int c = 0; c < 8; ++c)
                x[c] = bf2f(ph[c]) * (acc[c][r] + brv[c] * fs);
            float vjx = bf2f(vb.x), vjy = bf2f(vb.y), vjz = bf2f(vb.z);
            float u1x = srow[p][row][2], u1y = srow[p][row][3], u1z = srow[p][row][4];
            float u2x = srow[p][row][5], u2y = srow[p][row][6], u2z = srow[p][row][7];
            float u3x = srow[p][row][8], u3y = srow[p][row][9], u3z = srow[p][row][10];

            ds += x[0];
            d0 += vjx * x[1] + u1x * x[2] + u2x * x[3] + u3x * x[4]
                + x[5] * (vjy * u1z - vjz * u1y)
                + x[6] * (vjy * u2z - vjz * u2y)
                + x[7] * (vjy * u3z - vjz * u3y);
            d1 += vjy * x[1] + u1y * x[2] + u2y * x[3] + u3y * x[4]
                + x[5] * (vjz * u1x - vjx * u1z)
                + x[6] * (vjz * u2x - vjx * u2z)
                + x[7] * (vjz * u3x - vjx * u3z);
            d2 += vjz * x[1] + u1z * x[2] + u2z * x[3] + u3z * x[4]
                + x[5] * (vjx * u1y - vjy * u1x)
                + x[6] * (vjx * u2y - vjy * u2x)
                + x[7] * (vjx * u3y - vjy * u3x);
        }

        ds += __shfl_xor(ds, 16); ds += __shfl_xor(ds, 32);
        d0 += __shfl_xor(d0, 16); d0 += __shfl_xor(d0, 32);
        d1 += __shfl_xor(d1, 16); d1 += __shfl_xor(d1, 32);
        d2 += __shfl_xor(d2, 16); d2 += __shfl_xor(d2, 32);

        if (quad == 0) {
            atomicAdd(&out0[(size_t)node * 128 + fcol], ds);
            size_t vo = (size_t)node * 384 + fcol;
            atomicAdd(&out1[vo], d0);
            atomicAdd(&out1[vo + 128], d1);
            atomicAdd(&out1[vo + 256], d2);
        }
    }
}

// ---------------------------------------------------------------------------
extern "C" void kernel_launch(void* const* d_in, const int* in_sizes, int n_in,
                              void* d_out, int out_size, void* d_ws, size_t ws_size,
                              hipStream_t stream) {
    const float* s  = (const float*)d_in[0];
    const float* v  = (const float*)d_in[1];
    const float* R1 = (const float*)d_in[2];
    const float* R2 = (const float*)d_in[3];
    const float* R3 = (const float*)d_in[4];
    const float* f1 = (const float*)d_in[5];
    const float* f2 = (const float*)d_in[6];
    const float* f3 = (const float*)d_in[7];
    const float* u1 = (const float*)d_in[8];
    const float* u2 = (const float*)d_in[9];
    const float* u3 = (const float*)d_in[10];
    const int*  eix = (const int*)d_in[11];
    const float* W1 = (const float*)d_in[12];
    const float* b1 = (const float*)d_in[13];
    const float* W2 = (const float*)d_in[14];
    const float* b2 = (const float*)d_in[15];
    const float* Wr = (const float*)d_in[16];
    const float* br = (const float*)d_in[17];

    char* ws = (char*)d_ws;
    size_t off = 0;
    auto alloc = [&](size_t bytes) -> void* {
        void* p = ws + off;
        off = (off + bytes + 255) & ~(size_t)255;
        return p;
    };
    int* cnt       = (int*)alloc((size_t)N_NODES * 4);
    int* cursor    = (int*)alloc((size_t)N_NODES * 4);
    int* tile_node = (int*)alloc((size_t)MAXT * 4);
    int* tile_e0   = (int*)alloc((size_t)MAXT * 4);
    int* tile_cnt  = (int*)alloc((size_t)MAXT * 4);
    int* ntiles    = (int*)alloc(4);
    int* elist     = (int*)alloc((size_t)N_EDGES * 4);
    unsigned short* Rc   = (unsigned short*)alloc((size_t)N_EDGES * 32 * 2);
    float* fsum          = (float*)alloc((size_t)N_EDGES * 4);
    unsigned short* vbf2 = (unsigned short*)alloc((size_t)N_NODES * 128 * 4 * 2);
    unsigned short* phi2 = (unsigned short*)alloc((size_t)N_NODES * 1024 * 2);
    unsigned short* W1T  = (unsigned short*)alloc(128 * 128 * 2);
    unsigned short* W2T  = (unsigned short*)alloc(1024 * 128 * 2);
    unsigned short* WrT  = (unsigned short*)alloc(1024 * 32 * 2);
    (void)ws_size; (void)in_sizes; (void)n_in; (void)out_size;

    float* out0 = (float*)d_out;
    float* out1 = out0 + (size_t)N_NODES * 128;

    hipMemsetAsync(cnt, 0, (size_t)N_NODES * 4, stream);
    init_kernel<<<15000, 256, 0, stream>>>(s, v, eix, W1, W2, Wr,
                                           out0, out1, vbf2, cnt, W1T, W2T, WrT);
    scan_kernel<<<1, 1024, 0, stream>>>(cnt, cursor, tile_node, tile_e0, tile_cnt, ntiles);
    rc_kernel<<<5000, 256, 0, stream>>>(R1, R2, R3, f1, f2, f3, eix, cursor,
                                        Rc, fsum, elist);
    phi_kernel<<<628, 256, 0, stream>>>(s, W1T, b1, W2T, b2, phi2);
    msg_kernel<<<MSG_GRID, 512, 0, stream>>>(Rc, fsum, eix, phi2, vbf2, WrT, br,
                                             elist, tile_node, tile_e0, tile_cnt,
                                             ntiles, u1, u2, u3, out0, out1);
}